// Round 2
// baseline (1522.586 us; speedup 1.0000x reference)
//
#include <hip/hip_runtime.h>

// ---------------- problem constants ----------------
#define NE 8          // experts
#define CAP 5120      // capacity (static: int(1.25*16384*2/8))
#define NT 16384      // tokens (B*T)
#define CD 1024       // channel dim C
#define FCD 4096      // 4*C
#define TILES_M 40    // CAP/128

typedef __attribute__((ext_vector_type(8))) short short8;
typedef __attribute__((ext_vector_type(4))) float f32x4;

__device__ __forceinline__ unsigned short f2bf(float f) {
  unsigned int u = __builtin_bit_cast(unsigned int, f);
  u += 0x7FFFu + ((u >> 16) & 1u);   // RNE
  return (unsigned short)(u >> 16);
}
__device__ __forceinline__ float bf2f(unsigned short u) {
  unsigned int v = ((unsigned int)u) << 16;
  return __builtin_bit_cast(float, v);
}
// async global->LDS, 16B per lane. LDS dest must be wave-uniform base (+lane*16 implicit).
__device__ __forceinline__ void g2lds16(const unsigned short* g, unsigned short* l) {
  __builtin_amdgcn_global_load_lds(
      (const __attribute__((address_space(1))) unsigned int*)(unsigned long long)g,
      (__attribute__((address_space(3))) unsigned int*)l,
      16, 0, 0);
}

// ---------------- fills (avoid hipMemsetAsync in graph) ----------------
__global__ __launch_bounds__(256) void fill_i32_k(int* __restrict__ p, int v, int n) {
  int i = blockIdx.x * 256 + threadIdx.x;
  if (i < n) p[i] = v;
}
__global__ __launch_bounds__(256) void fill_zero_f32x4_k(float4* __restrict__ p, size_t n4) {
  size_t i = (size_t)blockIdx.x * 256 + threadIdx.x;
  if (i < n4) p[i] = make_float4(0.f, 0.f, 0.f, 0.f);
}

// ---------------- transpose + fp32->bf16 (weights) ----------------
// in: [R][Cc] fp32 row-major (+ blockIdx.z expert slice)  ->  out: [Cc][R] bf16
__global__ __launch_bounds__(256) void transpose_bf16_k(
    const float* __restrict__ in, unsigned short* __restrict__ out, int R, int Cc) {
  __shared__ float tile[64][65];
  const size_t esz = (size_t)R * Cc;
  const float* inp = in + (size_t)blockIdx.z * esz;
  unsigned short* outp = out + (size_t)blockIdx.z * esz;
  const int cbase = blockIdx.x * 64, rbase = blockIdx.y * 64;
  const int t = threadIdx.x;
#pragma unroll
  for (int i = 0; i < 4; ++i) {
    int idx = i * 256 + t;           // 0..1023
    int r = idx >> 4, c4 = (idx & 15) * 4;
    const float4 v = *reinterpret_cast<const float4*>(inp + (size_t)(rbase + r) * Cc + cbase + c4);
    tile[r][c4 + 0] = v.x; tile[r][c4 + 1] = v.y; tile[r][c4 + 2] = v.z; tile[r][c4 + 3] = v.w;
  }
  __syncthreads();
#pragma unroll
  for (int i = 0; i < 4; ++i) {
    int idx = i * 256 + t;
    int oc = idx >> 4, q = (idx & 15) * 4;
    ushort4 o;
    o.x = f2bf(tile[q + 0][oc]); o.y = f2bf(tile[q + 1][oc]);
    o.z = f2bf(tile[q + 2][oc]); o.w = f2bf(tile[q + 3][oc]);
    *reinterpret_cast<ushort4*>(outp + (size_t)(cbase + oc) * R + rbase + q) = o;
  }
}

// ---------------- router: fp64 logits, top-2, softmax; also x -> bf16 ----------------
__global__ __launch_bounds__(256) void router_k(
    const float* __restrict__ x, const float* __restrict__ wg,
    unsigned short* __restrict__ xb, int* __restrict__ topidx, float* __restrict__ probs) {
  __shared__ float wls[NE * CD];     // 32 KiB
  const int t = threadIdx.x;
  for (int i = t; i < NE * CD; i += 256) wls[i] = wg[i];
  __syncthreads();
  const int wave = t >> 6, lane = t & 63;
  const int gw = blockIdx.x * 4 + wave;         // 1024 waves total
  for (int it = 0; it < 16; ++it) {
    const int n = gw * 16 + it;
    const float* xr = x + (size_t)n * CD;
    double acc[NE] = {0, 0, 0, 0, 0, 0, 0, 0};
#pragma unroll 4
    for (int j = 0; j < 16; ++j) {
      int c = lane + j * 64;
      float xv = xr[c];
      xb[(size_t)n * CD + c] = f2bf(xv);
      double xd = (double)xv;
#pragma unroll
      for (int e = 0; e < NE; ++e) acc[e] += xd * (double)wls[e * CD + c];
    }
#pragma unroll
    for (int s = 32; s >= 1; s >>= 1) {
#pragma unroll
      for (int e = 0; e < NE; ++e) acc[e] += __shfl_xor(acc[e], s, 64);
    }
    if (lane == 0) {
      int i1 = 0; double v1 = acc[0];
      for (int e = 1; e < NE; ++e) if (acc[e] > v1) { v1 = acc[e]; i1 = e; }
      int i2 = -1; double v2 = -1e300;
      for (int e = 0; e < NE; ++e) if (e != i1 && acc[e] > v2) { v2 = acc[e]; i2 = e; }
      float l0 = (float)v1, l1 = (float)v2;
      float p0 = 1.0f / (1.0f + expf(l1 - l0));   // softmax of [l0,l1], l0 >= l1
      topidx[n * 2 + 0] = i1; topidx[n * 2 + 1] = i2;
      probs[n * 2 + 0] = p0; probs[n * 2 + 1] = 1.0f - p0;
    }
  }
}

// ---------------- per-block expert histograms (k=0 and k=1) ----------------
__global__ __launch_bounds__(256) void hist_k(const int* __restrict__ topidx, int* __restrict__ blkhist) {
  __shared__ int h[16];
  const int t = threadIdx.x;
  if (t < 16) h[t] = 0;
  __syncthreads();
  const int n = blockIdx.x * 256 + t;
  atomicAdd(&h[topidx[n * 2 + 0]], 1);
  atomicAdd(&h[8 + topidx[n * 2 + 1]], 1);
  __syncthreads();
  if (t < 16) blkhist[blockIdx.x * 16 + t] = h[t];
}

// ---------------- scan block histograms; totals + capped counts ----------------
// totals_cnt: [0..7]=total k0 per e, [8..15]=total k1 per e, [16..23]=cnt[e]=min(total,CAP)
__global__ void scan_k(const int* __restrict__ blkhist, int* __restrict__ blkoff, int* __restrict__ totals_cnt) {
  const int t = threadIdx.x;
  if (t < 16) {
    int s = 0;
    for (int b = 0; b < 64; ++b) { blkoff[b * 16 + t] = s; s += blkhist[b * 16 + t]; }
    totals_cnt[t] = s;
  }
  __syncthreads();
  if (t < 8) {
    int tot = totals_cnt[t] + totals_cnt[8 + t];
    totals_cnt[16 + t] = tot < CAP ? tot : CAP;
  }
}

// ---------------- ranks (k-major cumsum semantics) + slot_map scatter ----------------
// slotmap[e][rank] = n*2+k, or -1 if unfilled
__global__ __launch_bounds__(256) void rank_k(
    const int* __restrict__ topidx, const int* __restrict__ blkoff,
    const int* __restrict__ totals_cnt, int* __restrict__ ranks, int* __restrict__ slotmap) {
  __shared__ int wcnt[2][4][8];
  __shared__ int woff[2][4][8];
  const int t = threadIdx.x, wave = t >> 6, lane = t & 63;
  const int n = blockIdx.x * 256 + t;
  const int e1 = topidx[n * 2 + 0], e2 = topidx[n * 2 + 1];
  const unsigned long long lt = (1ull << lane) - 1ull;
  int pre1 = 0, pre2 = 0;
#pragma unroll
  for (int e = 0; e < 8; ++e) {
    unsigned long long m1 = __ballot(e1 == e);
    unsigned long long m2 = __ballot(e2 == e);
    if (e1 == e) pre1 = __popcll(m1 & lt);
    if (e2 == e) pre2 = __popcll(m2 & lt);
    if (lane == 0) { wcnt[0][wave][e] = __popcll(m1); wcnt[1][wave][e] = __popcll(m2); }
  }
  __syncthreads();
  if (t < 16) {
    int k = t >> 3, e = t & 7, s = 0;
    for (int w = 0; w < 4; ++w) { woff[k][w][e] = s; s += wcnt[k][w][e]; }
  }
  __syncthreads();
  int r1 = blkoff[blockIdx.x * 16 + e1] + woff[0][wave][e1] + pre1;
  int r2 = totals_cnt[e2] + blkoff[blockIdx.x * 16 + 8 + e2] + woff[1][wave][e2] + pre2;
  ranks[n * 2 + 0] = (r1 < CAP) ? r1 : -1;
  ranks[n * 2 + 1] = (r2 < CAP) ? r2 : -1;
  if (r1 < CAP) slotmap[e1 * CAP + r1] = n * 2 + 0;
  if (r2 < CAP) slotmap[e2 * CAP + r2] = n * 2 + 1;
}

// ---------------- bf16 MFMA GEMM, 128x128 tile, BK=64, m97-style 2-barrier loop ----------------
// A: GATHER ? xb[NT][KDIM] gathered via slotmap : H [le][CAP][KDIM] linear rows
// Bt: [le][NDIM][KDIM] (pre-transposed weights)
// !SCATTER: Out [le][CAP][NDIM] bf16.  SCATTER: outp[token][CD] += prob * val (non-atomic RMW;
//           safe only when each dispatch covers a single expert -> rows are distinct tokens).
// RELU2 => val = relu(acc)^2
template <int KDIM, int NDIM, bool GATHER, bool RELU2, bool SCATTER>
__global__ __launch_bounds__(256) void gemm_k(
    const unsigned short* __restrict__ A, const unsigned short* __restrict__ Bt,
    unsigned short* __restrict__ Out, const int* __restrict__ slotmap,
    const int* __restrict__ cnt, const float* __restrict__ probs,
    float* __restrict__ outp, int e_base) {
  constexpr int TILES_N = NDIM / 128;
  const int bid = blockIdx.x;
  const int le = bid / (TILES_M * TILES_N);        // local expert within this launch
  const int e = e_base + le;                       // global expert
  const int rem = bid % (TILES_M * TILES_N);
  const int mt = rem / TILES_N;
  const int nt = rem % TILES_N;
  if (mt * 128 >= cnt[e]) return;   // uniform early-exit

  __shared__ unsigned short lA[128 * 64];   // [row][k] 16 KiB
  __shared__ unsigned short lB[128 * 64];   // [col][k] 16 KiB

  const int t = threadIdx.x, wave = t >> 6, lane = t & 63;
  const int wr = wave >> 1, wc = wave & 1;

  // staging source pointers (4 x 16B chunks per thread per operand per K-tile)
  const unsigned short* srcA[4];
  const unsigned short* srcB[4];
#pragma unroll
  for (int i = 0; i < 4; ++i) {
    int li = (i * 4 + wave) * 64 + lane;    // 0..1023 (16B chunk index)
    int row = li >> 3;
    int ce = (li & 7) * 8;                  // element offset within row
    size_t arow;
    if (GATHER) {
      int sv = slotmap[e * CAP + mt * 128 + row];
      arow = (size_t)(sv < 0 ? 0 : (sv >> 1));   // unfilled slot -> harmless garbage row
    } else {
      arow = (size_t)le * CAP + mt * 128 + row;
    }
    srcA[i] = A + arow * KDIM + ce;
    srcB[i] = Bt + ((size_t)le * NDIM + nt * 128 + row) * KDIM + ce;
  }

  f32x4 acc[4][4] = {};
  const int l15 = lane & 15, l4 = lane >> 4;
  const unsigned short* pa = &lA[(wr * 64 + l15) * 64 + l4 * 8];
  const unsigned short* pb = &lB[(wc * 64 + l15) * 64 + l4 * 8];

  for (int kt = 0; kt < KDIM / 64; ++kt) {
    __syncthreads();                        // previous tile's ds_reads done
#pragma unroll
    for (int i = 0; i < 4; ++i) {
      g2lds16(srcA[i], &lA[(i * 4 + wave) * 512]);
      g2lds16(srcB[i], &lB[(i * 4 + wave) * 512]);
      srcA[i] += 64; srcB[i] += 64;
    }
    __syncthreads();                        // compiler drains vmcnt(0) before barrier
#pragma unroll
    for (int kk = 0; kk < 2; ++kk) {
      short8 a[4], b[4];
#pragma unroll
      for (int m = 0; m < 4; ++m) a[m] = *(const short8*)(pa + m * 1024 + kk * 32);
#pragma unroll
      for (int nf = 0; nf < 4; ++nf) b[nf] = *(const short8*)(pb + nf * 1024 + kk * 32);
#pragma unroll
      for (int m = 0; m < 4; ++m)
#pragma unroll
        for (int nf = 0; nf < 4; ++nf)
          acc[m][nf] = __builtin_amdgcn_mfma_f32_16x16x32_bf16(a[m], b[nf], acc[m][nf], 0, 0, 0);
    }
  }

  // epilogue: C/D layout col=lane&15, row=(lane>>4)*4+r  [m89/m91]
  const int mrow0 = mt * 128 + wr * 64;     // row within expert buffer
  const int colb = nt * 128 + wc * 64;
  if (SCATTER) {
#pragma unroll
    for (int m = 0; m < 4; ++m)
#pragma unroll
      for (int r = 0; r < 4; ++r) {
        const int rl = mrow0 + m * 16 + l4 * 4 + r;
        const int sv = slotmap[e * CAP + rl];
        if (sv < 0) continue;
        const float p = probs[sv];
        float* ob = outp + (size_t)(sv >> 1) * CD + colb + l15;
#pragma unroll
        for (int nf = 0; nf < 4; ++nf) {
          float v = acc[m][nf][r];
          if (RELU2) { v = fmaxf(v, 0.0f); v = v * v; }
          ob[nf * 16] += p * v;             // non-atomic RMW: rows unique per dispatch
        }
      }
  } else {
    const size_t rowb = (size_t)le * CAP + mrow0;
#pragma unroll
    for (int m = 0; m < 4; ++m)
#pragma unroll
      for (int nf = 0; nf < 4; ++nf)
#pragma unroll
        for (int r = 0; r < 4; ++r) {
          float v = acc[m][nf][r];
          if (RELU2) { v = fmaxf(v, 0.0f); v = v * v; }
          Out[(rowb + m * 16 + l4 * 4 + r) * NDIM + colb + nf * 16 + l15] = f2bf(v);
        }
  }
}

// ---------------- combine (big path): out[n] = sum_k p_k * eo[e_k][rank_k] ----------------
__global__ __launch_bounds__(256) void combine_k(
    const unsigned short* __restrict__ eo, const int* __restrict__ topidx,
    const float* __restrict__ probs, const int* __restrict__ ranks, float* __restrict__ out) {
  const int n = blockIdx.x, t = threadIdx.x;
  const int c = t * 4;
  const int e1 = topidx[n * 2 + 0], e2 = topidx[n * 2 + 1];
  const int r1 = ranks[n * 2 + 0], r2 = ranks[n * 2 + 1];
  const float p1 = probs[n * 2 + 0], p2 = probs[n * 2 + 1];
  float o0 = 0.f, o1 = 0.f, o2 = 0.f, o3 = 0.f;
  if (r1 >= 0) {
    const ushort4 v = *(const ushort4*)(eo + ((size_t)e1 * CAP + r1) * CD + c);
    o0 += p1 * bf2f(v.x); o1 += p1 * bf2f(v.y); o2 += p1 * bf2f(v.z); o3 += p1 * bf2f(v.w);
  }
  if (r2 >= 0) {
    const ushort4 v = *(const ushort4*)(eo + ((size_t)e2 * CAP + r2) * CD + c);
    o0 += p2 * bf2f(v.x); o1 += p2 * bf2f(v.y); o2 += p2 * bf2f(v.z); o3 += p2 * bf2f(v.w);
  }
  float4 o; o.x = o0; o.y = o1; o.z = o2; o.w = o3;
  *reinterpret_cast<float4*>(out + (size_t)n * CD + c) = o;
}

// ---------------- launch ----------------
extern "C" void kernel_launch(void* const* d_in, const int* in_sizes, int n_in,
                              void* d_out, int out_size, void* d_ws, size_t ws_size,
                              hipStream_t stream) {
  const float* x = (const float*)d_in[0];
  const float* wg = (const float*)d_in[1];
  const float* cfc = (const float*)d_in[2];
  const float* cproj = (const float*)d_in[3];
  float* out = (float*)d_out;
  char* ws = (char*)d_ws;
  (void)in_sizes; (void)n_in; (void)out_size;

  // ---- shared small buffers (both paths) ----
  size_t off = 0;
  auto alloc = [&](size_t bytes) { size_t o = off; off = (off + bytes + 255) & ~(size_t)255; return o; };
  unsigned short* XB = (unsigned short*)(ws + alloc((size_t)NT * CD * 2));   // x bf16: 32 MB
  int* TOPIDX  = (int*)(ws + alloc((size_t)NT * 2 * 4));
  float* PROBS = (float*)(ws + alloc((size_t)NT * 2 * 4));
  int* RANKS   = (int*)(ws + alloc((size_t)NT * 2 * 4));
  int* SLOTMAP = (int*)(ws + alloc((size_t)NE * CAP * 4));
  int* BLKHIST = (int*)(ws + alloc(64 * 16 * 4));
  int* BLKOFF  = (int*)(ws + alloc(64 * 16 * 4));
  int* TOTALS  = (int*)(ws + alloc(256));
  const size_t shared_end = off;

  // big-path layout
  size_t boff = shared_end;
  auto balloc = [&](size_t bytes) { size_t o = boff; boff = (boff + bytes + 255) & ~(size_t)255; return o; };
  const size_t oCFCT   = balloc((size_t)NE * FCD * CD * 2);   // 64 MB
  const size_t oCPROJT = balloc((size_t)NE * CD * FCD * 2);   // 64 MB
  const size_t oHBIG   = balloc((size_t)NE * CAP * FCD * 2);  // 320 MB
  const size_t oEO     = balloc((size_t)NE * CAP * CD * 2);   // 80 MB
  const size_t big_need = boff;

  // small-path layout
  size_t soff = shared_end;
  auto salloc = [&](size_t bytes) { size_t o = soff; soff = (soff + bytes + 255) & ~(size_t)255; return o; };
  const size_t oWT1 = salloc((size_t)FCD * CD * 2);           // 8 MB  (c_fc[e]^T)
  const size_t oWT2 = salloc((size_t)CD * FCD * 2);           // 8 MB  (c_proj[e]^T)
  const size_t oHS  = salloc((size_t)CAP * FCD * 2);          // 40 MB
  const size_t small_need = soff;

  if (ws_size < small_need) {
    // cannot run: controlled failure (zeros) instead of a memory fault
    fill_zero_f32x4_k<<<(NT * CD / 4 + 255) / 256, 256, 0, stream>>>((float4*)out, (size_t)NT * CD / 4);
    return;
  }
  const bool big = ws_size >= big_need;
  int* CNT = TOTALS + 16;

  // ---- common prologue ----
  fill_i32_k<<<(NE * CAP + 255) / 256, 256, 0, stream>>>(SLOTMAP, -1, NE * CAP);
  router_k<<<256, 256, 0, stream>>>(x, wg, XB, TOPIDX, PROBS);
  hist_k<<<64, 256, 0, stream>>>(TOPIDX, BLKHIST);
  scan_k<<<1, 64, 0, stream>>>(BLKHIST, BLKOFF, TOTALS);
  rank_k<<<64, 256, 0, stream>>>(TOPIDX, BLKOFF, TOTALS, RANKS, SLOTMAP);

  if (big) {
    unsigned short* CFCT   = (unsigned short*)(ws + oCFCT);
    unsigned short* CPROJT = (unsigned short*)(ws + oCPROJT);
    unsigned short* H      = (unsigned short*)(ws + oHBIG);
    unsigned short* EO     = (unsigned short*)(ws + oEO);
    transpose_bf16_k<<<dim3(FCD / 64, CD / 64, NE), 256, 0, stream>>>(cfc, CFCT, CD, FCD);
    transpose_bf16_k<<<dim3(CD / 64, FCD / 64, NE), 256, 0, stream>>>(cproj, CPROJT, FCD, CD);
    gemm_k<CD, FCD, true, true, false><<<NE * TILES_M * (FCD / 128), 256, 0, stream>>>(
        XB, CFCT, H, SLOTMAP, CNT, nullptr, nullptr, 0);
    gemm_k<FCD, CD, false, false, false><<<NE * TILES_M * (CD / 128), 256, 0, stream>>>(
        H, CPROJT, EO, SLOTMAP, CNT, nullptr, nullptr, 0);
    combine_k<<<NT, 256, 0, stream>>>(EO, TOPIDX, PROBS, RANKS, out);
  } else {
    unsigned short* WT1 = (unsigned short*)(ws + oWT1);
    unsigned short* WT2 = (unsigned short*)(ws + oWT2);
    unsigned short* H   = (unsigned short*)(ws + oHS);
    // out accumulates across experts -> zero it first
    fill_zero_f32x4_k<<<(NT * CD / 4 + 255) / 256, 256, 0, stream>>>((float4*)out, (size_t)NT * CD / 4);
    for (int e = 0; e < NE; ++e) {
      transpose_bf16_k<<<dim3(FCD / 64, CD / 64, 1), 256, 0, stream>>>(
          cfc + (size_t)e * CD * FCD, WT1, CD, FCD);
      transpose_bf16_k<<<dim3(CD / 64, FCD / 64, 1), 256, 0, stream>>>(
          cproj + (size_t)e * FCD * CD, WT2, FCD, CD);
      gemm_k<CD, FCD, true, true, false><<<TILES_M * (FCD / 128), 256, 0, stream>>>(
          XB, WT1, H, SLOTMAP, CNT, nullptr, nullptr, e);
      gemm_k<FCD, CD, false, false, true><<<TILES_M * (CD / 128), 256, 0, stream>>>(
          H, WT2, nullptr, SLOTMAP, CNT, PROBS, out, e);
    }
  }
}

// Round 3
// 1201.978 us; speedup vs baseline: 1.2667x; 1.2667x over previous
//
#include <hip/hip_runtime.h>

// ---------------- problem constants ----------------
#define NE 8          // experts
#define CAP 5120      // capacity (static: int(1.25*16384*2/8))
#define NT 16384      // tokens (B*T)
#define CD 1024       // channel dim C
#define FCD 4096      // 4*C
#define TILES_M 40    // CAP/128

typedef __attribute__((ext_vector_type(8))) short short8;
typedef __attribute__((ext_vector_type(4))) float f32x4;

__device__ __forceinline__ unsigned short f2bf(float f) {
  unsigned int u = __builtin_bit_cast(unsigned int, f);
  u += 0x7FFFu + ((u >> 16) & 1u);   // RNE
  return (unsigned short)(u >> 16);
}
__device__ __forceinline__ float bf2f(unsigned short u) {
  unsigned int v = ((unsigned int)u) << 16;
  return __builtin_bit_cast(float, v);
}
// async global->LDS, 16B per lane. LDS dest must be wave-uniform base (+lane*16 implicit).
__device__ __forceinline__ void g2lds16(const unsigned short* g, unsigned short* l) {
  __builtin_amdgcn_global_load_lds(
      (const __attribute__((address_space(1))) unsigned int*)(unsigned long long)g,
      (__attribute__((address_space(3))) unsigned int*)l,
      16, 0, 0);
}

// ---------------- fills (avoid hipMemsetAsync in graph) ----------------
__global__ __launch_bounds__(256) void fill_i32_k(int* __restrict__ p, int v, int n) {
  int i = blockIdx.x * 256 + threadIdx.x;
  if (i < n) p[i] = v;
}
__global__ __launch_bounds__(256) void fill_zero_f32x4_k(float4* __restrict__ p, size_t n4) {
  size_t i = (size_t)blockIdx.x * 256 + threadIdx.x;
  if (i < n4) p[i] = make_float4(0.f, 0.f, 0.f, 0.f);
}

// ---------------- transpose + fp32->bf16 (weights) ----------------
// in: [R][Cc] fp32 row-major (+ blockIdx.z expert slice)  ->  out: [Cc][R] bf16
__global__ __launch_bounds__(256) void transpose_bf16_k(
    const float* __restrict__ in, unsigned short* __restrict__ out, int R, int Cc) {
  __shared__ float tile[64][65];
  const size_t esz = (size_t)R * Cc;
  const float* inp = in + (size_t)blockIdx.z * esz;
  unsigned short* outp = out + (size_t)blockIdx.z * esz;
  const int cbase = blockIdx.x * 64, rbase = blockIdx.y * 64;
  const int t = threadIdx.x;
#pragma unroll
  for (int i = 0; i < 4; ++i) {
    int idx = i * 256 + t;           // 0..1023
    int r = idx >> 4, c4 = (idx & 15) * 4;
    const float4 v = *reinterpret_cast<const float4*>(inp + (size_t)(rbase + r) * Cc + cbase + c4);
    tile[r][c4 + 0] = v.x; tile[r][c4 + 1] = v.y; tile[r][c4 + 2] = v.z; tile[r][c4 + 3] = v.w;
  }
  __syncthreads();
#pragma unroll
  for (int i = 0; i < 4; ++i) {
    int idx = i * 256 + t;
    int oc = idx >> 4, q = (idx & 15) * 4;
    ushort4 o;
    o.x = f2bf(tile[q + 0][oc]); o.y = f2bf(tile[q + 1][oc]);
    o.z = f2bf(tile[q + 2][oc]); o.w = f2bf(tile[q + 3][oc]);
    *reinterpret_cast<ushort4*>(outp + (size_t)(cbase + oc) * R + rbase + q) = o;
  }
}

// ---------------- router: fp64 logits, top-2, softmax; also x -> bf16 ----------------
// 2048 blocks x 4 waves; 2 tokens per wave (vs old 256 blocks -> latency-starved, 140us @ 10.7% occ)
__global__ __launch_bounds__(256) void router_k(
    const float* __restrict__ x, const float* __restrict__ wg,
    unsigned short* __restrict__ xb, int* __restrict__ topidx, float* __restrict__ probs) {
  __shared__ float wls[NE * CD];     // 32 KiB
  const int t = threadIdx.x;
  {
    const float4* w4 = (const float4*)wg;
    float4* l4 = (float4*)wls;
    for (int i = t; i < NE * CD / 4; i += 256) l4[i] = w4[i];
  }
  __syncthreads();
  const int wave = t >> 6, lane = t & 63;
  const int gw = blockIdx.x * 4 + wave;         // 0..8191
  const float4* wls4 = (const float4*)wls;
#pragma unroll
  for (int it = 0; it < 2; ++it) {
    const int n = gw * 2 + it;
    const float4* xr4 = (const float4*)(x + (size_t)n * CD);
    ushort4* xb4 = (ushort4*)(xb + (size_t)n * CD);
    double acc[NE] = {0, 0, 0, 0, 0, 0, 0, 0};
#pragma unroll
    for (int j = 0; j < 4; ++j) {
      const int idx = j * 64 + lane;            // float4 index within row
      const float4 xv = xr4[idx];
      ushort4 o;
      o.x = f2bf(xv.x); o.y = f2bf(xv.y); o.z = f2bf(xv.z); o.w = f2bf(xv.w);
      xb4[idx] = o;
#pragma unroll
      for (int e = 0; e < NE; ++e) {
        const float4 wv = wls4[e * 256 + idx];
        acc[e] += (double)xv.x * (double)wv.x + (double)xv.y * (double)wv.y
                + (double)xv.z * (double)wv.z + (double)xv.w * (double)wv.w;
      }
    }
#pragma unroll
    for (int s = 32; s >= 1; s >>= 1) {
#pragma unroll
      for (int e = 0; e < NE; ++e) acc[e] += __shfl_xor(acc[e], s, 64);
    }
    if (lane == 0) {
      int i1 = 0; double v1 = acc[0];
      for (int e = 1; e < NE; ++e) if (acc[e] > v1) { v1 = acc[e]; i1 = e; }
      int i2 = -1; double v2 = -1e300;
      for (int e = 0; e < NE; ++e) if (e != i1 && acc[e] > v2) { v2 = acc[e]; i2 = e; }
      float p0 = 1.0f / (1.0f + expf((float)(v2 - v1)));   // softmax of [v1,v2], v1 >= v2
      topidx[n * 2 + 0] = i1; topidx[n * 2 + 1] = i2;
      probs[n * 2 + 0] = p0; probs[n * 2 + 1] = 1.0f - p0;
    }
  }
}

// ---------------- per-block expert histograms (k=0 and k=1) ----------------
__global__ __launch_bounds__(256) void hist_k(const int* __restrict__ topidx, int* __restrict__ blkhist) {
  __shared__ int h[16];
  const int t = threadIdx.x;
  if (t < 16) h[t] = 0;
  __syncthreads();
  const int n = blockIdx.x * 256 + t;
  atomicAdd(&h[topidx[n * 2 + 0]], 1);
  atomicAdd(&h[8 + topidx[n * 2 + 1]], 1);
  __syncthreads();
  if (t < 16) blkhist[blockIdx.x * 16 + t] = h[t];
}

// ---------------- scan block histograms; totals + capped counts ----------------
// totals_cnt: [0..7]=total k0 per e, [8..15]=total k1 per e, [16..23]=cnt[e]=min(total,CAP)
__global__ void scan_k(const int* __restrict__ blkhist, int* __restrict__ blkoff, int* __restrict__ totals_cnt) {
  const int t = threadIdx.x;
  if (t < 16) {
    int s = 0;
    for (int b = 0; b < 64; ++b) { blkoff[b * 16 + t] = s; s += blkhist[b * 16 + t]; }
    totals_cnt[t] = s;
  }
  __syncthreads();
  if (t < 8) {
    int tot = totals_cnt[t] + totals_cnt[8 + t];
    totals_cnt[16 + t] = tot < CAP ? tot : CAP;
  }
}

// ---------------- ranks (k-major cumsum semantics) + slot_map scatter ----------------
// slotmap[e][rank] = n*2+k, or -1 if unfilled
__global__ __launch_bounds__(256) void rank_k(
    const int* __restrict__ topidx, const int* __restrict__ blkoff,
    const int* __restrict__ totals_cnt, int* __restrict__ ranks, int* __restrict__ slotmap) {
  __shared__ int wcnt[2][4][8];
  __shared__ int woff[2][4][8];
  const int t = threadIdx.x, wave = t >> 6, lane = t & 63;
  const int n = blockIdx.x * 256 + t;
  const int e1 = topidx[n * 2 + 0], e2 = topidx[n * 2 + 1];
  const unsigned long long lt = (1ull << lane) - 1ull;
  int pre1 = 0, pre2 = 0;
#pragma unroll
  for (int e = 0; e < 8; ++e) {
    unsigned long long m1 = __ballot(e1 == e);
    unsigned long long m2 = __ballot(e2 == e);
    if (e1 == e) pre1 = __popcll(m1 & lt);
    if (e2 == e) pre2 = __popcll(m2 & lt);
    if (lane == 0) { wcnt[0][wave][e] = __popcll(m1); wcnt[1][wave][e] = __popcll(m2); }
  }
  __syncthreads();
  if (t < 16) {
    int k = t >> 3, e = t & 7, s = 0;
    for (int w = 0; w < 4; ++w) { woff[k][w][e] = s; s += wcnt[k][w][e]; }
  }
  __syncthreads();
  int r1 = blkoff[blockIdx.x * 16 + e1] + woff[0][wave][e1] + pre1;
  int r2 = totals_cnt[e2] + blkoff[blockIdx.x * 16 + 8 + e2] + woff[1][wave][e2] + pre2;
  ranks[n * 2 + 0] = (r1 < CAP) ? r1 : -1;
  ranks[n * 2 + 1] = (r2 < CAP) ? r2 : -1;
  if (r1 < CAP) slotmap[e1 * CAP + r1] = n * 2 + 0;
  if (r2 < CAP) slotmap[e2 * CAP + r2] = n * 2 + 1;
}

// ---------------- bf16 MFMA GEMM, 128x128 tile, BK=64, m97-style 2-barrier loop ----------------
// A: GATHER ? xb[NT][KDIM] gathered via slotmap : H [le][CAP][KDIM] linear rows
// Bt: [le][NDIM][KDIM] (pre-transposed weights; caller pre-offsets to e_base)
// !SCATTER: Out [le][CAP][NDIM] bf16 (caller pre-offsets to e_base).
// SCATTER: outp[token][CD] += prob * val (non-atomic RMW; safe only when the dispatch covers a
//          single expert -> rows are distinct tokens). RELU2 => val = relu(acc)^2
template <int KDIM, int NDIM, bool GATHER, bool RELU2, bool SCATTER>
__global__ __launch_bounds__(256) void gemm_k(
    const unsigned short* __restrict__ A, const unsigned short* __restrict__ Bt,
    unsigned short* __restrict__ Out, const int* __restrict__ slotmap,
    const int* __restrict__ cnt, const float* __restrict__ probs,
    float* __restrict__ outp, int e_base) {
  constexpr int TILES_N = NDIM / 128;
  const int bid = blockIdx.x;
  const int le = bid / (TILES_M * TILES_N);        // local expert within this launch
  const int e = e_base + le;                       // global expert
  const int rem = bid % (TILES_M * TILES_N);
  const int mt = rem / TILES_N;
  const int nt = rem % TILES_N;
  if (mt * 128 >= cnt[e]) return;   // uniform early-exit

  __shared__ unsigned short lA[128 * 64];   // [row][k] 16 KiB
  __shared__ unsigned short lB[128 * 64];   // [col][k] 16 KiB

  const int t = threadIdx.x, wave = t >> 6, lane = t & 63;
  const int wr = wave >> 1, wc = wave & 1;

  // staging source pointers (4 x 16B chunks per thread per operand per K-tile)
  const unsigned short* srcA[4];
  const unsigned short* srcB[4];
#pragma unroll
  for (int i = 0; i < 4; ++i) {
    int li = (i * 4 + wave) * 64 + lane;    // 0..1023 (16B chunk index)
    int row = li >> 3;
    int ce = (li & 7) * 8;                  // element offset within row
    size_t arow;
    if (GATHER) {
      int sv = slotmap[e * CAP + mt * 128 + row];
      arow = (size_t)(sv < 0 ? 0 : (sv >> 1));   // unfilled slot -> harmless garbage row
    } else {
      arow = (size_t)le * CAP + mt * 128 + row;
    }
    srcA[i] = A + arow * KDIM + ce;
    srcB[i] = Bt + ((size_t)le * NDIM + nt * 128 + row) * KDIM + ce;
  }

  f32x4 acc[4][4] = {};
  const int l15 = lane & 15, l4 = lane >> 4;
  const unsigned short* pa = &lA[(wr * 64 + l15) * 64 + l4 * 8];
  const unsigned short* pb = &lB[(wc * 64 + l15) * 64 + l4 * 8];

  for (int kt = 0; kt < KDIM / 64; ++kt) {
    __syncthreads();                        // previous tile's ds_reads done
#pragma unroll
    for (int i = 0; i < 4; ++i) {
      g2lds16(srcA[i], &lA[(i * 4 + wave) * 512]);
      g2lds16(srcB[i], &lB[(i * 4 + wave) * 512]);
      srcA[i] += 64; srcB[i] += 64;
    }
    __syncthreads();                        // compiler drains vmcnt(0) before barrier
#pragma unroll
    for (int kk = 0; kk < 2; ++kk) {
      short8 a[4], b[4];
#pragma unroll
      for (int m = 0; m < 4; ++m) a[m] = *(const short8*)(pa + m * 1024 + kk * 32);
#pragma unroll
      for (int nf = 0; nf < 4; ++nf) b[nf] = *(const short8*)(pb + nf * 1024 + kk * 32);
#pragma unroll
      for (int m = 0; m < 4; ++m)
#pragma unroll
        for (int nf = 0; nf < 4; ++nf)
          acc[m][nf] = __builtin_amdgcn_mfma_f32_16x16x32_bf16(a[m], b[nf], acc[m][nf], 0, 0, 0);
    }
  }

  // epilogue: C/D layout col=lane&15, row=(lane>>4)*4+r  [m89/m91]
  const int mrow0 = mt * 128 + wr * 64;     // row within expert buffer
  const int colb = nt * 128 + wc * 64;
  if (SCATTER) {
#pragma unroll
    for (int m = 0; m < 4; ++m)
#pragma unroll
      for (int r = 0; r < 4; ++r) {
        const int rl = mrow0 + m * 16 + l4 * 4 + r;
        const int sv = slotmap[e * CAP + rl];
        if (sv < 0) continue;
        const float p = probs[sv];
        float* ob = outp + (size_t)(sv >> 1) * CD + colb + l15;
#pragma unroll
        for (int nf = 0; nf < 4; ++nf) {
          float v = acc[m][nf][r];
          if (RELU2) { v = fmaxf(v, 0.0f); v = v * v; }
          ob[nf * 16] += p * v;             // non-atomic RMW: rows unique per dispatch
        }
      }
  } else {
    const size_t rowb = (size_t)le * CAP + mrow0;
#pragma unroll
    for (int m = 0; m < 4; ++m)
#pragma unroll
      for (int nf = 0; nf < 4; ++nf)
#pragma unroll
        for (int r = 0; r < 4; ++r) {
          float v = acc[m][nf][r];
          if (RELU2) { v = fmaxf(v, 0.0f); v = v * v; }
          Out[(rowb + m * 16 + l4 * 4 + r) * NDIM + colb + nf * 16 + l15] = f2bf(v);
        }
  }
}

// ---------------- combine (EO tiers): out[n] = sum_k p_k * eo[e_k][rank_k] ----------------
__global__ __launch_bounds__(256) void combine_k(
    const unsigned short* __restrict__ eo, const int* __restrict__ topidx,
    const float* __restrict__ probs, const int* __restrict__ ranks, float* __restrict__ out) {
  const int n = blockIdx.x, t = threadIdx.x;
  const int c = t * 4;
  const int e1 = topidx[n * 2 + 0], e2 = topidx[n * 2 + 1];
  const int r1 = ranks[n * 2 + 0], r2 = ranks[n * 2 + 1];
  const float p1 = probs[n * 2 + 0], p2 = probs[n * 2 + 1];
  float o0 = 0.f, o1 = 0.f, o2 = 0.f, o3 = 0.f;
  if (r1 >= 0) {
    const ushort4 v = *(const ushort4*)(eo + ((size_t)e1 * CAP + r1) * CD + c);
    o0 += p1 * bf2f(v.x); o1 += p1 * bf2f(v.y); o2 += p1 * bf2f(v.z); o3 += p1 * bf2f(v.w);
  }
  if (r2 >= 0) {
    const ushort4 v = *(const ushort4*)(eo + ((size_t)e2 * CAP + r2) * CD + c);
    o0 += p2 * bf2f(v.x); o1 += p2 * bf2f(v.y); o2 += p2 * bf2f(v.z); o3 += p2 * bf2f(v.w);
  }
  float4 o; o.x = o0; o.y = o1; o.z = o2; o.w = o3;
  *reinterpret_cast<float4*>(out + (size_t)n * CD + c) = o;
}

// ---------------- launch ----------------
extern "C" void kernel_launch(void* const* d_in, const int* in_sizes, int n_in,
                              void* d_out, int out_size, void* d_ws, size_t ws_size,
                              hipStream_t stream) {
  const float* x = (const float*)d_in[0];
  const float* wg = (const float*)d_in[1];
  const float* cfc = (const float*)d_in[2];
  const float* cproj = (const float*)d_in[3];
  float* out = (float*)d_out;
  char* ws = (char*)d_ws;
  (void)in_sizes; (void)n_in; (void)out_size;

  const size_t W1SZ = (size_t)FCD * CD * 2;    // one expert's transposed weight: 8 MB
  const size_t HSZ  = (size_t)CAP * FCD * 2;   // one expert's hidden: 40 MB
  const size_t EOSZ = (size_t)CAP * CD * 2;    // one expert's output: 10 MB

  // ---- shared small buffers (all tiers) ----
  size_t off = 0;
  auto alloc = [&](size_t bytes) { size_t o = off; off = (off + bytes + 255) & ~(size_t)255; return o; };
  unsigned short* XB = (unsigned short*)(ws + alloc((size_t)NT * CD * 2));   // x bf16: 32 MB
  int* TOPIDX  = (int*)(ws + alloc((size_t)NT * 2 * 4));
  float* PROBS = (float*)(ws + alloc((size_t)NT * 2 * 4));
  int* RANKS   = (int*)(ws + alloc((size_t)NT * 2 * 4));
  int* SLOTMAP = (int*)(ws + alloc((size_t)NE * CAP * 4));
  int* BLKHIST = (int*)(ws + alloc(64 * 16 * 4));
  int* BLKOFF  = (int*)(ws + alloc(64 * 16 * 4));
  int* TOTALS  = (int*)(ws + alloc(256));
  const size_t shared_end = off;
  int* CNT = TOTALS + 16;

  // hoisted-weights layout (tiers W/S)
  size_t woff = shared_end;
  auto walloc = [&](size_t bytes) { size_t o = woff; woff = (woff + bytes + 255) & ~(size_t)255; return o; };
  const size_t oCFCT   = walloc(NE * W1SZ);   // 64 MB
  const size_t oCPROJT = walloc(NE * W1SZ);   // 64 MB
  const size_t weights_end = woff;

  // pick tier: largest EG in {8,4,2,1} such that weights + EO(all) + EG*H fits
  int EG = 0;
  for (int g = 8; g >= 1; g >>= 1) {
    size_t need = weights_end + NE * EOSZ + 512 + (size_t)g * HSZ + 512;
    if (ws_size >= need) { EG = g; break; }
  }
  const bool tierS = (EG == 0) && (ws_size >= weights_end + HSZ + 512);
  const bool tierF = (EG == 0) && !tierS &&
                     (ws_size >= shared_end + 2 * W1SZ + HSZ + 1024);

  if (EG == 0 && !tierS && !tierF) {
    fill_zero_f32x4_k<<<(NT * CD / 4 + 255) / 256, 256, 0, stream>>>((float4*)out, (size_t)NT * CD / 4);
    return;   // controlled failure instead of memory fault
  }

  // ---- common prologue ----
  fill_i32_k<<<(NE * CAP + 255) / 256, 256, 0, stream>>>(SLOTMAP, -1, NE * CAP);
  router_k<<<2048, 256, 0, stream>>>(x, wg, XB, TOPIDX, PROBS);
  hist_k<<<64, 256, 0, stream>>>(TOPIDX, BLKHIST);
  scan_k<<<1, 64, 0, stream>>>(BLKHIST, BLKOFF, TOTALS);
  rank_k<<<64, 256, 0, stream>>>(TOPIDX, BLKOFF, TOTALS, RANKS, SLOTMAP);

  if (EG > 0 || tierS) {
    unsigned short* CFCT   = (unsigned short*)(ws + oCFCT);
    unsigned short* CPROJT = (unsigned short*)(ws + oCPROJT);
    // hoisted all-expert weight transposes (2 dispatches)
    transpose_bf16_k<<<dim3(FCD / 64, CD / 64, NE), 256, 0, stream>>>(cfc, CFCT, CD, FCD);
    transpose_bf16_k<<<dim3(CD / 64, FCD / 64, NE), 256, 0, stream>>>(cproj, CPROJT, FCD, CD);

    if (EG > 0) {
      // tier W: grouped GEMMs + EO + one combine
      size_t eoff = weights_end;
      auto ealloc = [&](size_t bytes) { size_t o = eoff; eoff = (eoff + bytes + 255) & ~(size_t)255; return o; };
      unsigned short* EO = (unsigned short*)(ws + ealloc(NE * EOSZ));
      unsigned short* H  = (unsigned short*)(ws + ealloc((size_t)EG * HSZ));
      for (int g = 0; g < NE / EG; ++g) {
        const int eb = g * EG;
        gemm_k<CD, FCD, true, true, false><<<EG * TILES_M * (FCD / 128), 256, 0, stream>>>(
            XB, CFCT + (size_t)eb * FCD * CD, H, SLOTMAP, CNT, nullptr, nullptr, eb);
        gemm_k<FCD, CD, false, false, false><<<EG * TILES_M * (CD / 128), 256, 0, stream>>>(
            H, CPROJT + (size_t)eb * CD * FCD, EO + (size_t)eb * CAP * CD, SLOTMAP, CNT,
            nullptr, nullptr, eb);
      }
      combine_k<<<NT, 256, 0, stream>>>(EO, TOPIDX, PROBS, RANKS, out);
    } else {
      // tier S: per-expert scatter-G2 (no EO)
      unsigned short* H = (unsigned short*)(ws + weights_end);
      fill_zero_f32x4_k<<<(NT * CD / 4 + 255) / 256, 256, 0, stream>>>((float4*)out, (size_t)NT * CD / 4);
      for (int e = 0; e < NE; ++e) {
        gemm_k<CD, FCD, true, true, false><<<TILES_M * (FCD / 128), 256, 0, stream>>>(
            XB, CFCT + (size_t)e * FCD * CD, H, SLOTMAP, CNT, nullptr, nullptr, e);
        gemm_k<FCD, CD, false, false, true><<<TILES_M * (CD / 128), 256, 0, stream>>>(
            H, CPROJT + (size_t)e * CD * FCD, nullptr, SLOTMAP, CNT, PROBS, out, e);
      }
    }
  } else {
    // tier F: per-expert transposes (minimum footprint ~89 MB)
    size_t soff = shared_end;
    auto salloc = [&](size_t bytes) { size_t o = soff; soff = (soff + bytes + 255) & ~(size_t)255; return o; };
    unsigned short* WT1 = (unsigned short*)(ws + salloc(W1SZ));
    unsigned short* WT2 = (unsigned short*)(ws + salloc(W1SZ));
    unsigned short* H   = (unsigned short*)(ws + salloc(HSZ));
    fill_zero_f32x4_k<<<(NT * CD / 4 + 255) / 256, 256, 0, stream>>>((float4*)out, (size_t)NT * CD / 4);
    for (int e = 0; e < NE; ++e) {
      transpose_bf16_k<<<dim3(FCD / 64, CD / 64, 1), 256, 0, stream>>>(
          cfc + (size_t)e * CD * FCD, WT1, CD, FCD);
      transpose_bf16_k<<<dim3(CD / 64, FCD / 64, 1), 256, 0, stream>>>(
          cproj + (size_t)e * FCD * CD, WT2, FCD, CD);
      gemm_k<CD, FCD, true, true, false><<<TILES_M * (FCD / 128), 256, 0, stream>>>(
          XB, WT1, H, SLOTMAP, CNT, nullptr, nullptr, e);
      gemm_k<FCD, CD, false, false, true><<<TILES_M * (CD / 128), 256, 0, stream>>>(
          H, WT2, nullptr, SLOTMAP, CNT, PROBS, out, e);
    }
  }
}

// Round 4
// 993.291 us; speedup vs baseline: 1.5329x; 1.2101x over previous
//
#include <hip/hip_runtime.h>

// ---------------- problem constants ----------------
#define NE 8          // experts
#define CAP 5120      // capacity (static: int(1.25*16384*2/8))
#define NT 16384      // tokens (B*T)
#define CD 1024       // channel dim C
#define FCD 4096      // 4*C

typedef __attribute__((ext_vector_type(8))) short short8;
typedef __attribute__((ext_vector_type(4))) float f32x4;

__device__ __forceinline__ unsigned short f2bf(float f) {
  unsigned int u = __builtin_bit_cast(unsigned int, f);
  u += 0x7FFFu + ((u >> 16) & 1u);   // RNE
  return (unsigned short)(u >> 16);
}
__device__ __forceinline__ float bf2f(unsigned short u) {
  unsigned int v = ((unsigned int)u) << 16;
  return __builtin_bit_cast(float, v);
}
// async global->LDS, 16B per lane. LDS dest must be wave-uniform base (+lane*16 implicit).
__device__ __forceinline__ void g2lds16(const unsigned short* g, unsigned short* l) {
  __builtin_amdgcn_global_load_lds(
      (const __attribute__((address_space(1))) unsigned int*)(unsigned long long)g,
      (__attribute__((address_space(3))) unsigned int*)l,
      16, 0, 0);
}

// ---------------- fills (avoid hipMemsetAsync in graph) ----------------
__global__ __launch_bounds__(256) void fill_i32_k(int* __restrict__ p, int v, int n) {
  int i = blockIdx.x * 256 + threadIdx.x;
  if (i < n) p[i] = v;
}
__global__ __launch_bounds__(256) void fill_zero_f32x4_k(float4* __restrict__ p, size_t n4) {
  size_t i = (size_t)blockIdx.x * 256 + threadIdx.x;
  if (i < n4) p[i] = make_float4(0.f, 0.f, 0.f, 0.f);
}

// ---------------- transpose + fp32->bf16 (weights) ----------------
__global__ __launch_bounds__(256) void transpose_bf16_k(
    const float* __restrict__ in, unsigned short* __restrict__ out, int R, int Cc) {
  __shared__ float tile[64][65];
  const size_t esz = (size_t)R * Cc;
  const float* inp = in + (size_t)blockIdx.z * esz;
  unsigned short* outp = out + (size_t)blockIdx.z * esz;
  const int cbase = blockIdx.x * 64, rbase = blockIdx.y * 64;
  const int t = threadIdx.x;
#pragma unroll
  for (int i = 0; i < 4; ++i) {
    int idx = i * 256 + t;
    int r = idx >> 4, c4 = (idx & 15) * 4;
    const float4 v = *reinterpret_cast<const float4*>(inp + (size_t)(rbase + r) * Cc + cbase + c4);
    tile[r][c4 + 0] = v.x; tile[r][c4 + 1] = v.y; tile[r][c4 + 2] = v.z; tile[r][c4 + 3] = v.w;
  }
  __syncthreads();
#pragma unroll
  for (int i = 0; i < 4; ++i) {
    int idx = i * 256 + t;
    int oc = idx >> 4, q = (idx & 15) * 4;
    ushort4 o;
    o.x = f2bf(tile[q + 0][oc]); o.y = f2bf(tile[q + 1][oc]);
    o.z = f2bf(tile[q + 2][oc]); o.w = f2bf(tile[q + 3][oc]);
    *reinterpret_cast<ushort4*>(outp + (size_t)(cbase + oc) * R + rbase + q) = o;
  }
}

// ---------------- router: fp64 logits, top-2, softmax; also x -> bf16 ----------------
__global__ __launch_bounds__(256) void router_k(
    const float* __restrict__ x, const float* __restrict__ wg,
    unsigned short* __restrict__ xb, int* __restrict__ topidx, float* __restrict__ probs) {
  __shared__ float wls[NE * CD];
  const int t = threadIdx.x;
  {
    const float4* w4 = (const float4*)wg;
    float4* l4 = (float4*)wls;
    for (int i = t; i < NE * CD / 4; i += 256) l4[i] = w4[i];
  }
  __syncthreads();
  const int wave = t >> 6, lane = t & 63;
  const int gw = blockIdx.x * 4 + wave;
  const float4* wls4 = (const float4*)wls;
#pragma unroll
  for (int it = 0; it < 2; ++it) {
    const int n = gw * 2 + it;
    const float4* xr4 = (const float4*)(x + (size_t)n * CD);
    ushort4* xb4 = (ushort4*)(xb + (size_t)n * CD);
    double acc[NE] = {0, 0, 0, 0, 0, 0, 0, 0};
#pragma unroll
    for (int j = 0; j < 4; ++j) {
      const int idx = j * 64 + lane;
      const float4 xv = xr4[idx];
      ushort4 o;
      o.x = f2bf(xv.x); o.y = f2bf(xv.y); o.z = f2bf(xv.z); o.w = f2bf(xv.w);
      xb4[idx] = o;
#pragma unroll
      for (int e = 0; e < NE; ++e) {
        const float4 wv = wls4[e * 256 + idx];
        acc[e] += (double)xv.x * (double)wv.x + (double)xv.y * (double)wv.y
                + (double)xv.z * (double)wv.z + (double)xv.w * (double)wv.w;
      }
    }
#pragma unroll
    for (int s = 32; s >= 1; s >>= 1) {
#pragma unroll
      for (int e = 0; e < NE; ++e) acc[e] += __shfl_xor(acc[e], s, 64);
    }
    if (lane == 0) {
      int i1 = 0; double v1 = acc[0];
      for (int e = 1; e < NE; ++e) if (acc[e] > v1) { v1 = acc[e]; i1 = e; }
      int i2 = -1; double v2 = -1e300;
      for (int e = 0; e < NE; ++e) if (e != i1 && acc[e] > v2) { v2 = acc[e]; i2 = e; }
      float p0 = 1.0f / (1.0f + expf((float)(v2 - v1)));
      topidx[n * 2 + 0] = i1; topidx[n * 2 + 1] = i2;
      probs[n * 2 + 0] = p0; probs[n * 2 + 1] = 1.0f - p0;
    }
  }
}

// ---------------- per-block expert histograms ----------------
__global__ __launch_bounds__(256) void hist_k(const int* __restrict__ topidx, int* __restrict__ blkhist) {
  __shared__ int h[16];
  const int t = threadIdx.x;
  if (t < 16) h[t] = 0;
  __syncthreads();
  const int n = blockIdx.x * 256 + t;
  atomicAdd(&h[topidx[n * 2 + 0]], 1);
  atomicAdd(&h[8 + topidx[n * 2 + 1]], 1);
  __syncthreads();
  if (t < 16) blkhist[blockIdx.x * 16 + t] = h[t];
}

// ---------------- scan ----------------
__global__ void scan_k(const int* __restrict__ blkhist, int* __restrict__ blkoff, int* __restrict__ totals_cnt) {
  const int t = threadIdx.x;
  if (t < 16) {
    int s = 0;
    for (int b = 0; b < 64; ++b) { blkoff[b * 16 + t] = s; s += blkhist[b * 16 + t]; }
    totals_cnt[t] = s;
  }
  __syncthreads();
  if (t < 8) {
    int tot = totals_cnt[t] + totals_cnt[8 + t];
    totals_cnt[16 + t] = tot < CAP ? tot : CAP;
  }
}

// ---------------- ranks + slot_map scatter (slotmap[e][rank] = n*2+k) ----------------
__global__ __launch_bounds__(256) void rank_k(
    const int* __restrict__ topidx, const int* __restrict__ blkoff,
    const int* __restrict__ totals_cnt, int* __restrict__ ranks, int* __restrict__ slotmap) {
  __shared__ int wcnt[2][4][8];
  __shared__ int woff[2][4][8];
  const int t = threadIdx.x, wave = t >> 6, lane = t & 63;
  const int n = blockIdx.x * 256 + t;
  const int e1 = topidx[n * 2 + 0], e2 = topidx[n * 2 + 1];
  const unsigned long long lt = (1ull << lane) - 1ull;
  int pre1 = 0, pre2 = 0;
#pragma unroll
  for (int e = 0; e < 8; ++e) {
    unsigned long long m1 = __ballot(e1 == e);
    unsigned long long m2 = __ballot(e2 == e);
    if (e1 == e) pre1 = __popcll(m1 & lt);
    if (e2 == e) pre2 = __popcll(m2 & lt);
    if (lane == 0) { wcnt[0][wave][e] = __popcll(m1); wcnt[1][wave][e] = __popcll(m2); }
  }
  __syncthreads();
  if (t < 16) {
    int k = t >> 3, e = t & 7, s = 0;
    for (int w = 0; w < 4; ++w) { woff[k][w][e] = s; s += wcnt[k][w][e]; }
  }
  __syncthreads();
  int r1 = blkoff[blockIdx.x * 16 + e1] + woff[0][wave][e1] + pre1;
  int r2 = totals_cnt[e2] + blkoff[blockIdx.x * 16 + 8 + e2] + woff[1][wave][e2] + pre2;
  ranks[n * 2 + 0] = (r1 < CAP) ? r1 : -1;
  ranks[n * 2 + 1] = (r2 < CAP) ? r2 : -1;
  if (r1 < CAP) slotmap[e1 * CAP + r1] = n * 2 + 0;
  if (r2 < CAP) slotmap[e2 * CAP + r2] = n * 2 + 1;
}

// ============ pipelined MFMA GEMM: BK=32, 3-slot LDS, counted vmcnt, T2 swizzle ============
// 8 waves as 2(M) x 4(N). BM in {256,128}; BN=256 fixed. Per-wave tile (BM/2) x 64.
// LDS layout per slot: [row][32] shorts, 16B chunk c of row stored at chunk c^(row&3) (T2).
// Staged via global_load_lds with pre-swizzled per-lane SOURCE (rule #21), linear LDS dest.
// Sync: per K-tile t: { vmcnt(VWAIT) ; s_barrier } then 2 phases of
// { ds_read frags ; issue stage for t+2 into slot (t+2)%3 ; lgkmcnt(0)+sched_barrier ;
//   setprio(1) MFMAx(8*M_REP/2) setprio(0) }.
// Race-free: slot (t+2)%3 == slot (t-1)%3, whose reads all completed (lgkmcnt(0) per wave)
// before every wave crossed the top-of-t barrier; stage issues only after that barrier.
// vmcnt(VWAIT) at top of t leaves exactly K-tile (t+1)'s VWAIT loads in flight (T4, never 0).
template <int BM, int KDIM, int NDIM, bool GATHER, bool RELU2>
__global__ __launch_bounds__(512) void gemm8_k(
    const unsigned short* __restrict__ A, const unsigned short* __restrict__ Bt,
    unsigned short* __restrict__ Out, const int* __restrict__ slotmap,
    const int* __restrict__ cnt, int e_base) {
  constexpr int KT = KDIM / 32;
  constexpr int TM = CAP / BM;
  constexpr int TN = NDIM / 256;
  constexpr int M_REP = BM / 32;       // frags per wave in M (8 or 4)
  constexpr int MH = M_REP / 2;
  constexpr int ALOADS = BM / 128;     // 16B loads per thread per A K-tile (2 or 1)
  constexpr int VWAIT = ALOADS + 2;    // loads per wave per K-tile

  __shared__ unsigned short lA[3][BM * 32];   // 3 slots
  __shared__ unsigned short lB[3][256 * 32];

  // T1: bijective XCD swizzle (m204); grid always divisible by 8 here
  const int nwg = gridDim.x;
  const int q = nwg >> 3, r = nwg & 7;
  const int xcd = blockIdx.x & 7, lin = blockIdx.x >> 3;
  const int wg = (xcd < r ? xcd * (q + 1) : r * (q + 1) + (xcd - r) * q) + lin;
  const int le = wg / (TM * TN);
  const int rem = wg % (TM * TN);
  const int nt = rem / TM;            // mt fastest: XCD chunk shares B-panel
  const int mt = rem % TM;
  const int e = e_base + le;
  if (mt * BM >= cnt[e]) return;      // uniform early-exit

  const int tid = threadIdx.x;
  const int wave = tid >> 6, lane = tid & 63;
  const int wr = wave >> 2, wc = wave & 3;
  const int l15 = lane & 15, l4 = lane >> 4;

  // global staging sources (per-lane, with T2-swizzled k-chunk folded in)
  const unsigned short* pA[ALOADS];
  const unsigned short* pB[2];
#pragma unroll
  for (int j = 0; j < ALOADS; ++j) {
    const int ci = j * 512 + tid;            // 16B chunk index in slot
    const int row = ci >> 2, cst = ci & 3;
    const int csrc = cst ^ (row & 3);
    size_t grow;
    if (GATHER) {
      const int sv = slotmap[e * CAP + mt * BM + row];
      grow = (size_t)(sv < 0 ? 0 : (sv >> 1));   // unfilled -> harmless garbage row
    } else {
      grow = (size_t)le * CAP + mt * BM + row;
    }
    pA[j] = A + grow * KDIM + csrc * 8;
  }
#pragma unroll
  for (int j = 0; j < 2; ++j) {
    const int ci = j * 512 + tid;
    const int row = ci >> 2, cst = ci & 3;
    const int csrc = cst ^ (row & 3);
    pB[j] = Bt + ((size_t)le * NDIM + nt * 256 + row) * KDIM + csrc * 8;
  }

  // LDS fragment read offsets (shorts), T2 swizzle on chunk
  int aOff[M_REP], bOff[4];
#pragma unroll
  for (int m = 0; m < M_REP; ++m)
    aOff[m] = (wr * (BM / 2) + m * 16 + l15) * 32 + ((l4 ^ (l15 & 3)) * 8);
#pragma unroll
  for (int n = 0; n < 4; ++n)
    bOff[n] = (wc * 64 + n * 16 + l15) * 32 + ((l4 ^ (l15 & 3)) * 8);

  f32x4 acc[M_REP][4] = {};

  // prologue: stage K-tiles 0,1 -> slots 0,1 (FIFO: A then B per tile)
#pragma unroll
  for (int kt = 0; kt < 2; ++kt) {
#pragma unroll
    for (int j = 0; j < ALOADS; ++j)
      g2lds16(pA[j] + kt * 32, &lA[kt][(j * 512 + wave * 64) * 8]);
#pragma unroll
    for (int j = 0; j < 2; ++j)
      g2lds16(pB[j] + kt * 32, &lB[kt][(j * 512 + wave * 64) * 8]);
  }

  for (int t = 0; t < KT; ++t) {
    if (t < KT - 1) {
      if constexpr (VWAIT == 4) asm volatile("s_waitcnt vmcnt(4)" ::: "memory");
      else                      asm volatile("s_waitcnt vmcnt(3)" ::: "memory");
    } else {
      asm volatile("s_waitcnt vmcnt(0)" ::: "memory");
    }
    __builtin_amdgcn_s_barrier();
    asm volatile("" ::: "memory");          // no LDS reads hoisted above barrier

    const int s = t % 3, s2 = (t + 2) % 3;
    const unsigned short* sA = &lA[s][0];
    const unsigned short* sB = &lB[s][0];
    const bool pf = (t + 2 < KT);

    // ---- phase 1: quadrant m0..MH-1 x all n ----
    short8 aF[MH], bF[4];
#pragma unroll
    for (int m = 0; m < MH; ++m) aF[m] = *(const short8*)(sA + aOff[m]);
#pragma unroll
    for (int n = 0; n < 4; ++n) bF[n] = *(const short8*)(sB + bOff[n]);
    if (pf) {
#pragma unroll
      for (int j = 0; j < ALOADS; ++j)
        g2lds16(pA[j] + (t + 2) * 32, &lA[s2][(j * 512 + wave * 64) * 8]);
    }
    asm volatile("s_waitcnt lgkmcnt(0)" ::: "memory");
    __builtin_amdgcn_sched_barrier(0);      // rule #18: MFMA must not hoist above wait
    __builtin_amdgcn_s_setprio(1);
#pragma unroll
    for (int m = 0; m < MH; ++m)
#pragma unroll
      for (int n = 0; n < 4; ++n)
        acc[m][n] = __builtin_amdgcn_mfma_f32_16x16x32_bf16(aF[m], bF[n], acc[m][n], 0, 0, 0);
    __builtin_amdgcn_s_setprio(0);

    // ---- phase 2: quadrant m MH..M_REP-1 (reuses bF) ----
    short8 aG[MH];
#pragma unroll
    for (int m = 0; m < MH; ++m) aG[m] = *(const short8*)(sA + aOff[MH + m]);
    if (pf) {
#pragma unroll
      for (int j = 0; j < 2; ++j)
        g2lds16(pB[j] + (t + 2) * 32, &lB[s2][(j * 512 + wave * 64) * 8]);
    }
    asm volatile("s_waitcnt lgkmcnt(0)" ::: "memory");
    __builtin_amdgcn_sched_barrier(0);
    __builtin_amdgcn_s_setprio(1);
#pragma unroll
    for (int m = 0; m < MH; ++m)
#pragma unroll
      for (int n = 0; n < 4; ++n)
        acc[MH + m][n] = __builtin_amdgcn_mfma_f32_16x16x32_bf16(aG[m], bF[n], acc[MH + m][n], 0, 0, 0);
    __builtin_amdgcn_s_setprio(0);
  }

  // epilogue: C/D layout col=lane&15, row=(lane>>4)*4+r
  const size_t rowb = (size_t)le * CAP + mt * BM + wr * (BM / 2);
  const int colb = nt * 256 + wc * 64;
#pragma unroll
  for (int m = 0; m < M_REP; ++m)
#pragma unroll
    for (int n = 0; n < 4; ++n)
#pragma unroll
      for (int rr = 0; rr < 4; ++rr) {
        float v = acc[m][n][rr];
        if (RELU2) { v = fmaxf(v, 0.0f); v = v * v; }
        Out[(rowb + m * 16 + l4 * 4 + rr) * NDIM + colb + n * 16 + l15] = f2bf(v);
      }
}

// ---------------- combine: out[n] = sum_k p_k * eo[e_k][rank_k] ----------------
__global__ __launch_bounds__(256) void combine_k(
    const unsigned short* __restrict__ eo, const int* __restrict__ topidx,
    const float* __restrict__ probs, const int* __restrict__ ranks, float* __restrict__ out) {
  const int n = blockIdx.x, t = threadIdx.x;
  const int c = t * 4;
  const int e1 = topidx[n * 2 + 0], e2 = topidx[n * 2 + 1];
  const int r1 = ranks[n * 2 + 0], r2 = ranks[n * 2 + 1];
  const float p1 = probs[n * 2 + 0], p2 = probs[n * 2 + 1];
  float o0 = 0.f, o1 = 0.f, o2 = 0.f, o3 = 0.f;
  if (r1 >= 0) {
    const ushort4 v = *(const ushort4*)(eo + ((size_t)e1 * CAP + r1) * CD + c);
    o0 += p1 * bf2f(v.x); o1 += p1 * bf2f(v.y); o2 += p1 * bf2f(v.z); o3 += p1 * bf2f(v.w);
  }
  if (r2 >= 0) {
    const ushort4 v = *(const ushort4*)(eo + ((size_t)e2 * CAP + r2) * CD + c);
    o0 += p2 * bf2f(v.x); o1 += p2 * bf2f(v.y); o2 += p2 * bf2f(v.z); o3 += p2 * bf2f(v.w);
  }
  float4 o; o.x = o0; o.y = o1; o.z = o2; o.w = o3;
  *reinterpret_cast<float4*>(out + (size_t)n * CD + c) = o;
}

// ---------------- launch ----------------
extern "C" void kernel_launch(void* const* d_in, const int* in_sizes, int n_in,
                              void* d_out, int out_size, void* d_ws, size_t ws_size,
                              hipStream_t stream) {
  const float* x = (const float*)d_in[0];
  const float* wg = (const float*)d_in[1];
  const float* cfc = (const float*)d_in[2];
  const float* cproj = (const float*)d_in[3];
  float* out = (float*)d_out;
  char* ws = (char*)d_ws;
  (void)in_sizes; (void)n_in; (void)out_size;

  const size_t W1SZ = (size_t)FCD * CD * 2;    // 8 MB per expert weight (bf16, transposed)
  const size_t HSZ  = (size_t)CAP * FCD * 2;   // 40 MB per expert hidden
  const size_t EOSZ = (size_t)CAP * CD * 2;    // 10 MB per expert output

  size_t off = 0;
  auto alloc = [&](size_t bytes) { size_t o = off; off = (off + bytes + 255) & ~(size_t)255; return o; };
  unsigned short* XB = (unsigned short*)(ws + alloc((size_t)NT * CD * 2));   // 32 MB
  int* TOPIDX  = (int*)(ws + alloc((size_t)NT * 2 * 4));
  float* PROBS = (float*)(ws + alloc((size_t)NT * 2 * 4));
  int* RANKS   = (int*)(ws + alloc((size_t)NT * 2 * 4));
  int* SLOTMAP = (int*)(ws + alloc((size_t)NE * CAP * 4));
  int* BLKHIST = (int*)(ws + alloc(64 * 16 * 4));
  int* BLKOFF  = (int*)(ws + alloc(64 * 16 * 4));
  int* TOTALS  = (int*)(ws + alloc(256));
  const size_t shared_end = off;
  int* CNT = TOTALS + 16;

  size_t woff = shared_end;
  auto walloc = [&](size_t bytes) { size_t o = woff; woff = (woff + bytes + 255) & ~(size_t)255; return o; };
  const size_t oCFCT   = walloc(NE * W1SZ);   // 64 MB
  const size_t oCPROJT = walloc(NE * W1SZ);   // 64 MB
  const size_t weights_end = woff;

  // pick largest EG in {8,4,2,1}: weights + EO(all) + EG*H
  int EG = 0;
  for (int g = 8; g >= 1; g >>= 1) {
    size_t need = weights_end + NE * EOSZ + 512 + (size_t)g * HSZ + 512;
    if (ws_size >= need) { EG = g; break; }
  }
  if (EG == 0) {
    fill_zero_f32x4_k<<<(NT * CD / 4 + 255) / 256, 256, 0, stream>>>((float4*)out, (size_t)NT * CD / 4);
    return;   // controlled failure instead of memory fault (ws >= 402MB observed, won't hit)
  }

  // prologue
  fill_i32_k<<<(NE * CAP + 255) / 256, 256, 0, stream>>>(SLOTMAP, -1, NE * CAP);
  router_k<<<2048, 256, 0, stream>>>(x, wg, XB, TOPIDX, PROBS);
  hist_k<<<64, 256, 0, stream>>>(TOPIDX, BLKHIST);
  scan_k<<<1, 64, 0, stream>>>(BLKHIST, BLKOFF, TOTALS);
  rank_k<<<64, 256, 0, stream>>>(TOPIDX, BLKOFF, TOTALS, RANKS, SLOTMAP);

  unsigned short* CFCT   = (unsigned short*)(ws + oCFCT);
  unsigned short* CPROJT = (unsigned short*)(ws + oCPROJT);
  transpose_bf16_k<<<dim3(FCD / 64, CD / 64, NE), 256, 0, stream>>>(cfc, CFCT, CD, FCD);
  transpose_bf16_k<<<dim3(CD / 64, FCD / 64, NE), 256, 0, stream>>>(cproj, CPROJT, FCD, CD);

  size_t eoff = weights_end;
  auto ealloc = [&](size_t bytes) { size_t o = eoff; eoff = (eoff + bytes + 255) & ~(size_t)255; return o; };
  unsigned short* EO = (unsigned short*)(ws + ealloc(NE * EOSZ));
  unsigned short* H  = (unsigned short*)(ws + ealloc((size_t)EG * HSZ));

  for (int g = 0; g < NE / EG; ++g) {
    const int eb = g * EG;
    // G1: [cap x 1024] x [1024 x 4096] -> H (relu^2), gathered A
    gemm8_k<256, CD, FCD, true, true><<<EG * (CAP / 256) * (FCD / 256), 512, 0, stream>>>(
        XB, CFCT + (size_t)eb * FCD * CD, H, SLOTMAP, CNT, eb);
    // G2: [cap x 4096] x [4096 x 1024] -> EO
    gemm8_k<128, FCD, CD, false, false><<<EG * (CAP / 128) * (CD / 256), 512, 0, stream>>>(
        H, CPROJT + (size_t)eb * CD * FCD, EO + (size_t)eb * CAP * CD, SLOTMAP, CNT, eb);
  }
  combine_k<<<NT, 256, 0, stream>>>(EO, TOPIDX, PROBS, RANKS, out);
}

// Round 5
// 993.112 us; speedup vs baseline: 1.5331x; 1.0002x over previous
//
#include <hip/hip_runtime.h>

// ---------------- problem constants ----------------
#define NE 8          // experts
#define CAP 5120      // capacity (static: int(1.25*16384*2/8))
#define NT 16384      // tokens (B*T)
#define CD 1024       // channel dim C
#define FCD 4096      // 4*C

typedef __attribute__((ext_vector_type(8))) short short8;
typedef __attribute__((ext_vector_type(4))) float f32x4;

__device__ __forceinline__ unsigned short f2bf(float f) {
  unsigned int u = __builtin_bit_cast(unsigned int, f);
  u += 0x7FFFu + ((u >> 16) & 1u);   // RNE
  return (unsigned short)(u >> 16);
}
__device__ __forceinline__ float bf2f(unsigned short u) {
  unsigned int v = ((unsigned int)u) << 16;
  return __builtin_bit_cast(float, v);
}
// async global->LDS, 16B per lane. LDS dest must be wave-uniform base (+lane*16 implicit).
__device__ __forceinline__ void g2lds16(const unsigned short* g, unsigned short* l) {
  __builtin_amdgcn_global_load_lds(
      (const __attribute__((address_space(1))) unsigned int*)(unsigned long long)g,
      (__attribute__((address_space(3))) unsigned int*)l,
      16, 0, 0);
}

// ---------------- fills (avoid hipMemsetAsync in graph) ----------------
__global__ __launch_bounds__(256) void fill_i32_k(int* __restrict__ p, int v, int n) {
  int i = blockIdx.x * 256 + threadIdx.x;
  if (i < n) p[i] = v;
}
__global__ __launch_bounds__(256) void fill_zero_f32x4_k(float4* __restrict__ p, size_t n4) {
  size_t i = (size_t)blockIdx.x * 256 + threadIdx.x;
  if (i < n4) p[i] = make_float4(0.f, 0.f, 0.f, 0.f);
}

// ---------------- transpose + fp32->bf16 (weights) ----------------
__global__ __launch_bounds__(256) void transpose_bf16_k(
    const float* __restrict__ in, unsigned short* __restrict__ out, int R, int Cc) {
  __shared__ float tile[64][65];
  const size_t esz = (size_t)R * Cc;
  const float* inp = in + (size_t)blockIdx.z * esz;
  unsigned short* outp = out + (size_t)blockIdx.z * esz;
  const int cbase = blockIdx.x * 64, rbase = blockIdx.y * 64;
  const int t = threadIdx.x;
#pragma unroll
  for (int i = 0; i < 4; ++i) {
    int idx = i * 256 + t;
    int r = idx >> 4, c4 = (idx & 15) * 4;
    const float4 v = *reinterpret_cast<const float4*>(inp + (size_t)(rbase + r) * Cc + cbase + c4);
    tile[r][c4 + 0] = v.x; tile[r][c4 + 1] = v.y; tile[r][c4 + 2] = v.z; tile[r][c4 + 3] = v.w;
  }
  __syncthreads();
#pragma unroll
  for (int i = 0; i < 4; ++i) {
    int idx = i * 256 + t;
    int oc = idx >> 4, q = (idx & 15) * 4;
    ushort4 o;
    o.x = f2bf(tile[q + 0][oc]); o.y = f2bf(tile[q + 1][oc]);
    o.z = f2bf(tile[q + 2][oc]); o.w = f2bf(tile[q + 3][oc]);
    *reinterpret_cast<ushort4*>(outp + (size_t)(cbase + oc) * R + rbase + q) = o;
  }
}

// ---------------- router: fp64 logits, top-2, softmax; also x -> bf16 ----------------
__global__ __launch_bounds__(256) void router_k(
    const float* __restrict__ x, const float* __restrict__ wg,
    unsigned short* __restrict__ xb, int* __restrict__ topidx, float* __restrict__ probs) {
  __shared__ float wls[NE * CD];
  const int t = threadIdx.x;
  {
    const float4* w4 = (const float4*)wg;
    float4* l4 = (float4*)wls;
    for (int i = t; i < NE * CD / 4; i += 256) l4[i] = w4[i];
  }
  __syncthreads();
  const int wave = t >> 6, lane = t & 63;
  const int gw = blockIdx.x * 4 + wave;
  const float4* wls4 = (const float4*)wls;
#pragma unroll
  for (int it = 0; it < 2; ++it) {
    const int n = gw * 2 + it;
    const float4* xr4 = (const float4*)(x + (size_t)n * CD);
    ushort4* xb4 = (ushort4*)(xb + (size_t)n * CD);
    double acc[NE] = {0, 0, 0, 0, 0, 0, 0, 0};
#pragma unroll
    for (int j = 0; j < 4; ++j) {
      const int idx = j * 64 + lane;
      const float4 xv = xr4[idx];
      ushort4 o;
      o.x = f2bf(xv.x); o.y = f2bf(xv.y); o.z = f2bf(xv.z); o.w = f2bf(xv.w);
      xb4[idx] = o;
#pragma unroll
      for (int e = 0; e < NE; ++e) {
        const float4 wv = wls4[e * 256 + idx];
        acc[e] += (double)xv.x * (double)wv.x + (double)xv.y * (double)wv.y
                + (double)xv.z * (double)wv.z + (double)xv.w * (double)wv.w;
      }
    }
#pragma unroll
    for (int s = 32; s >= 1; s >>= 1) {
#pragma unroll
      for (int e = 0; e < NE; ++e) acc[e] += __shfl_xor(acc[e], s, 64);
    }
    if (lane == 0) {
      int i1 = 0; double v1 = acc[0];
      for (int e = 1; e < NE; ++e) if (acc[e] > v1) { v1 = acc[e]; i1 = e; }
      int i2 = -1; double v2 = -1e300;
      for (int e = 0; e < NE; ++e) if (e != i1 && acc[e] > v2) { v2 = acc[e]; i2 = e; }
      float p0 = 1.0f / (1.0f + expf((float)(v2 - v1)));
      topidx[n * 2 + 0] = i1; topidx[n * 2 + 1] = i2;
      probs[n * 2 + 0] = p0; probs[n * 2 + 1] = 1.0f - p0;
    }
  }
}

// ---------------- per-block expert histograms ----------------
__global__ __launch_bounds__(256) void hist_k(const int* __restrict__ topidx, int* __restrict__ blkhist) {
  __shared__ int h[16];
  const int t = threadIdx.x;
  if (t < 16) h[t] = 0;
  __syncthreads();
  const int n = blockIdx.x * 256 + t;
  atomicAdd(&h[topidx[n * 2 + 0]], 1);
  atomicAdd(&h[8 + topidx[n * 2 + 1]], 1);
  __syncthreads();
  if (t < 16) blkhist[blockIdx.x * 16 + t] = h[t];
}

// ---------------- scan ----------------
__global__ void scan_k(const int* __restrict__ blkhist, int* __restrict__ blkoff, int* __restrict__ totals_cnt) {
  const int t = threadIdx.x;
  if (t < 16) {
    int s = 0;
    for (int b = 0; b < 64; ++b) { blkoff[b * 16 + t] = s; s += blkhist[b * 16 + t]; }
    totals_cnt[t] = s;
  }
  __syncthreads();
  if (t < 8) {
    int tot = totals_cnt[t] + totals_cnt[8 + t];
    totals_cnt[16 + t] = tot < CAP ? tot : CAP;
  }
}

// ---------------- ranks + slot_map scatter (slotmap[e][rank] = n*2+k) ----------------
__global__ __launch_bounds__(256) void rank_k(
    const int* __restrict__ topidx, const int* __restrict__ blkoff,
    const int* __restrict__ totals_cnt, int* __restrict__ ranks, int* __restrict__ slotmap) {
  __shared__ int wcnt[2][4][8];
  __shared__ int woff[2][4][8];
  const int t = threadIdx.x, wave = t >> 6, lane = t & 63;
  const int n = blockIdx.x * 256 + t;
  const int e1 = topidx[n * 2 + 0], e2 = topidx[n * 2 + 1];
  const unsigned long long lt = (1ull << lane) - 1ull;
  int pre1 = 0, pre2 = 0;
#pragma unroll
  for (int e = 0; e < 8; ++e) {
    unsigned long long m1 = __ballot(e1 == e);
    unsigned long long m2 = __ballot(e2 == e);
    if (e1 == e) pre1 = __popcll(m1 & lt);
    if (e2 == e) pre2 = __popcll(m2 & lt);
    if (lane == 0) { wcnt[0][wave][e] = __popcll(m1); wcnt[1][wave][e] = __popcll(m2); }
  }
  __syncthreads();
  if (t < 16) {
    int k = t >> 3, e = t & 7, s = 0;
    for (int w = 0; w < 4; ++w) { woff[k][w][e] = s; s += wcnt[k][w][e]; }
  }
  __syncthreads();
  int r1 = blkoff[blockIdx.x * 16 + e1] + woff[0][wave][e1] + pre1;
  int r2 = totals_cnt[e2] + blkoff[blockIdx.x * 16 + 8 + e2] + woff[1][wave][e2] + pre2;
  ranks[n * 2 + 0] = (r1 < CAP) ? r1 : -1;
  ranks[n * 2 + 1] = (r2 < CAP) ? r2 : -1;
  if (r1 < CAP) slotmap[e1 * CAP + r1] = n * 2 + 0;
  if (r2 < CAP) slotmap[e2 * CAP + r2] = n * 2 + 1;
}

// ============ pipelined MFMA GEMM: BK=32, 3-slot LDS, counted vmcnt, T2 swizzle ============
// WM x WN waves; per-wave tile (BM/WM) x (BN/WN). BK=32.
// LDS per slot: [row][32] shorts; 16B chunk c of row stored at c ^ ((row>>1)&3) (T2).
//   (row stride = 64B = 16 banks -> bank base repeats every 2 rows; XOR with (row>>1)&3 gives
//    exactly 2 lanes/bank-quad per 16-lane group = conflict-free per m136.)
// Staged via global_load_lds with pre-swizzled per-lane SOURCE (rule #21), linear LDS dest.
// Sync per K-tile t: { vmcnt(4) ; s_barrier } then 2 phases of
// { ds_read frags ; issue stage(t+2) into slot (t+2)%3 ; lgkmcnt(0)+sched_barrier ;
//   setprio(1) MFMA cluster setprio(0) }.
// Race-free: slot (t+2)%3 == slot (t-1)%3, whose reads completed (per-wave lgkmcnt(0)) before
// every wave crossed the top-of-t barrier; stage issues only after that barrier.
// vmcnt(4) leaves exactly K-tile (t+1)'s 4 loads/wave in flight (T4, never 0 until last tile).
template <int WM, int WN, int BM, int BN, int KDIM, int NDIM, bool GATHER, bool RELU2>
__global__ __launch_bounds__(WM * WN * 64) void gemm8_k(
    const unsigned short* __restrict__ A, const unsigned short* __restrict__ Bt,
    unsigned short* __restrict__ Out, const int* __restrict__ slotmap,
    const int* __restrict__ cnt, int e_base) {
  constexpr int THREADS = WM * WN * 64;
  constexpr int KT = KDIM / 32;
  constexpr int TM = CAP / BM;
  constexpr int TN = NDIM / BN;
  constexpr int M_REP = BM / WM / 16;
  constexpr int N_REP = BN / WN / 16;
  constexpr int MH = M_REP / 2;
  constexpr int ALOADS = BM * 4 / THREADS;   // 16B chunks per thread per A K-tile
  constexpr int BLOADS = BN * 4 / THREADS;
  static_assert(ALOADS + BLOADS == 4, "vmcnt literal assumes 4 loads/wave/tile");

  __shared__ unsigned short lA[3][BM * 32];
  __shared__ unsigned short lB[3][BN * 32];

  // T1: bijective XCD swizzle (m204)
  const int nwg = gridDim.x;
  const int q = nwg >> 3, r = nwg & 7;
  const int xcd = blockIdx.x & 7, lin = blockIdx.x >> 3;
  const int wg = (xcd < r ? xcd * (q + 1) : r * (q + 1) + (xcd - r) * q) + lin;
  const int le = wg / (TM * TN);
  const int rem = wg % (TM * TN);
  const int nt = rem / TM;            // mt fastest: XCD chunk shares B-panel
  const int mt = rem % TM;
  const int e = e_base + le;
  if (mt * BM >= cnt[e]) return;      // uniform early-exit

  const int tid = threadIdx.x;
  const int wave = tid >> 6, lane = tid & 63;
  const int wr = wave / WN, wc = wave % WN;
  const int l15 = lane & 15, l4 = lane >> 4;

  // global staging sources (per-lane, T2 pre-swizzled k-chunk)
  const unsigned short* pA[ALOADS];
  const unsigned short* pB[BLOADS];
#pragma unroll
  for (int j = 0; j < ALOADS; ++j) {
    const int ci = j * THREADS + tid;          // 16B chunk index in slot
    const int row = ci >> 2, cst = ci & 3;
    const int csrc = cst ^ ((row >> 1) & 3);
    size_t grow;
    if (GATHER) {
      const int sv = slotmap[e * CAP + mt * BM + row];
      grow = (size_t)(sv < 0 ? 0 : (sv >> 1));   // unfilled -> harmless garbage row
    } else {
      grow = (size_t)le * CAP + mt * BM + row;
    }
    pA[j] = A + grow * KDIM + csrc * 8;
  }
#pragma unroll
  for (int j = 0; j < BLOADS; ++j) {
    const int ci = j * THREADS + tid;
    const int row = ci >> 2, cst = ci & 3;
    const int csrc = cst ^ ((row >> 1) & 3);
    pB[j] = Bt + ((size_t)le * NDIM + nt * BN + row) * KDIM + csrc * 8;
  }

  // LDS fragment read offsets (shorts); row = base + l15 with base a multiple of 16,
  // so (row>>1)&3 == (l15>>1)&3
  const int ksw = (l4 ^ ((l15 >> 1) & 3)) * 8;
  int aOff[M_REP], bOff[N_REP];
#pragma unroll
  for (int m = 0; m < M_REP; ++m)
    aOff[m] = (wr * (BM / WM) + m * 16 + l15) * 32 + ksw;
#pragma unroll
  for (int n = 0; n < N_REP; ++n)
    bOff[n] = (wc * (BN / WN) + n * 16 + l15) * 32 + ksw;

  f32x4 acc[M_REP][N_REP] = {};

  // prologue: stage K-tiles 0,1 -> slots 0,1 (FIFO: A then B per tile)
#pragma unroll
  for (int kt = 0; kt < 2; ++kt) {
#pragma unroll
    for (int j = 0; j < ALOADS; ++j)
      g2lds16(pA[j] + kt * 32, &lA[kt][(j * THREADS + wave * 64) * 8]);
#pragma unroll
    for (int j = 0; j < BLOADS; ++j)
      g2lds16(pB[j] + kt * 32, &lB[kt][(j * THREADS + wave * 64) * 8]);
  }

  for (int t = 0; t < KT; ++t) {
    if (t < KT - 1) asm volatile("s_waitcnt vmcnt(4)" ::: "memory");
    else            asm volatile("s_waitcnt vmcnt(0)" ::: "memory");
    __builtin_amdgcn_s_barrier();
    asm volatile("" ::: "memory");          // no LDS reads hoisted above barrier

    const int s = t % 3, s2 = (t + 2) % 3;
    const unsigned short* sA = &lA[s][0];
    const unsigned short* sB = &lB[s][0];
    const bool pf = (t + 2 < KT);

    // ---- phase 1: m 0..MH-1 x all n ----
    short8 aF[MH], bF[N_REP];
#pragma unroll
    for (int m = 0; m < MH; ++m) aF[m] = *(const short8*)(sA + aOff[m]);
#pragma unroll
    for (int n = 0; n < N_REP; ++n) bF[n] = *(const short8*)(sB + bOff[n]);
    if (pf) {
#pragma unroll
      for (int j = 0; j < ALOADS; ++j)
        g2lds16(pA[j] + (t + 2) * 32, &lA[s2][(j * THREADS + wave * 64) * 8]);
    }
    asm volatile("s_waitcnt lgkmcnt(0)" ::: "memory");
    __builtin_amdgcn_sched_barrier(0);      // rule #18: MFMA must not hoist above wait
    __builtin_amdgcn_s_setprio(1);
#pragma unroll
    for (int m = 0; m < MH; ++m)
#pragma unroll
      for (int n = 0; n < N_REP; ++n)
        acc[m][n] = __builtin_amdgcn_mfma_f32_16x16x32_bf16(aF[m], bF[n], acc[m][n], 0, 0, 0);
    __builtin_amdgcn_s_setprio(0);

    // ---- phase 2: m MH..M_REP-1 (reuses bF) ----
    short8 aG[MH];
#pragma unroll
    for (int m = 0; m < MH; ++m) aG[m] = *(const short8*)(sA + aOff[MH + m]);
    if (pf) {
#pragma unroll
      for (int j = 0; j < BLOADS; ++j)
        g2lds16(pB[j] + (t + 2) * 32, &lB[s2][(j * THREADS + wave * 64) * 8]);
    }
    asm volatile("s_waitcnt lgkmcnt(0)" ::: "memory");
    __builtin_amdgcn_sched_barrier(0);
    __builtin_amdgcn_s_setprio(1);
#pragma unroll
    for (int m = 0; m < MH; ++m)
#pragma unroll
      for (int n = 0; n < N_REP; ++n)
        acc[MH + m][n] = __builtin_amdgcn_mfma_f32_16x16x32_bf16(aG[m], bF[n], acc[MH + m][n], 0, 0, 0);
    __builtin_amdgcn_s_setprio(0);
  }

  // epilogue: C/D layout col=lane&15, row=(lane>>4)*4+r
  const size_t rowb = (size_t)le * CAP + mt * BM + wr * (BM / WM);
  const int colb = nt * BN + wc * (BN / WN);
#pragma unroll
  for (int m = 0; m < M_REP; ++m)
#pragma unroll
    for (int n = 0; n < N_REP; ++n)
#pragma unroll
      for (int rr = 0; rr < 4; ++rr) {
        float v = acc[m][n][rr];
        if (RELU2) { v = fmaxf(v, 0.0f); v = v * v; }
        Out[(rowb + m * 16 + l4 * 4 + rr) * NDIM + colb + n * 16 + l15] = f2bf(v);
      }
}

// ---------------- combine: out[n] = sum_k p_k * eo[e_k][rank_k] ----------------
__global__ __launch_bounds__(256) void combine_k(
    const unsigned short* __restrict__ eo, const int* __restrict__ topidx,
    const float* __restrict__ probs, const int* __restrict__ ranks, float* __restrict__ out) {
  const int n = blockIdx.x, t = threadIdx.x;
  const int c = t * 4;
  const int e1 = topidx[n * 2 + 0], e2 = topidx[n * 2 + 1];
  const int r1 = ranks[n * 2 + 0], r2 = ranks[n * 2 + 1];
  const float p1 = probs[n * 2 + 0], p2 = probs[n * 2 + 1];
  float o0 = 0.f, o1 = 0.f, o2 = 0.f, o3 = 0.f;
  if (r1 >= 0) {
    const ushort4 v = *(const ushort4*)(eo + ((size_t)e1 * CAP + r1) * CD + c);
    o0 += p1 * bf2f(v.x); o1 += p1 * bf2f(v.y); o2 += p1 * bf2f(v.z); o3 += p1 * bf2f(v.w);
  }
  if (r2 >= 0) {
    const ushort4 v = *(const ushort4*)(eo + ((size_t)e2 * CAP + r2) * CD + c);
    o0 += p2 * bf2f(v.x); o1 += p2 * bf2f(v.y); o2 += p2 * bf2f(v.z); o3 += p2 * bf2f(v.w);
  }
  float4 o; o.x = o0; o.y = o1; o.z = o2; o.w = o3;
  *reinterpret_cast<float4*>(out + (size_t)n * CD + c) = o;
}

// ---------------- launch ----------------
extern "C" void kernel_launch(void* const* d_in, const int* in_sizes, int n_in,
                              void* d_out, int out_size, void* d_ws, size_t ws_size,
                              hipStream_t stream) {
  const float* x = (const float*)d_in[0];
  const float* wg = (const float*)d_in[1];
  const float* cfc = (const float*)d_in[2];
  const float* cproj = (const float*)d_in[3];
  float* out = (float*)d_out;
  char* ws = (char*)d_ws;
  (void)in_sizes; (void)n_in; (void)out_size;

  const size_t W1SZ = (size_t)FCD * CD * 2;    // 8 MB per expert weight (bf16, transposed)
  const size_t HSZ  = (size_t)CAP * FCD * 2;   // 40 MB per expert hidden
  const size_t EOSZ = (size_t)CAP * CD * 2;    // 10 MB per expert output

  size_t off = 0;
  auto alloc = [&](size_t bytes) { size_t o = off; off = (off + bytes + 255) & ~(size_t)255; return o; };
  unsigned short* XB = (unsigned short*)(ws + alloc((size_t)NT * CD * 2));   // 32 MB
  int* TOPIDX  = (int*)(ws + alloc((size_t)NT * 2 * 4));
  float* PROBS = (float*)(ws + alloc((size_t)NT * 2 * 4));
  int* RANKS   = (int*)(ws + alloc((size_t)NT * 2 * 4));
  int* SLOTMAP = (int*)(ws + alloc((size_t)NE * CAP * 4));
  int* BLKHIST = (int*)(ws + alloc(64 * 16 * 4));
  int* BLKOFF  = (int*)(ws + alloc(64 * 16 * 4));
  int* TOTALS  = (int*)(ws + alloc(256));
  const size_t shared_end = off;
  int* CNT = TOTALS + 16;

  size_t woff = shared_end;
  auto walloc = [&](size_t bytes) { size_t o = woff; woff = (woff + bytes + 255) & ~(size_t)255; return o; };
  const size_t oCFCT   = walloc(NE * W1SZ);   // 64 MB
  const size_t oCPROJT = walloc(NE * W1SZ);   // 64 MB
  const size_t weights_end = woff;

  // pick largest EG in {8,4,2,1}: weights + EO(all) + EG*H
  int EG = 0;
  for (int g = 8; g >= 1; g >>= 1) {
    size_t need = weights_end + NE * EOSZ + 512 + (size_t)g * HSZ + 512;
    if (ws_size >= need) { EG = g; break; }
  }
  if (EG == 0) {
    fill_zero_f32x4_k<<<(NT * CD / 4 + 255) / 256, 256, 0, stream>>>((float4*)out, (size_t)NT * CD / 4);
    return;   // controlled failure instead of memory fault (ws >= 402MB observed, won't hit)
  }

  // prologue
  fill_i32_k<<<(NE * CAP + 255) / 256, 256, 0, stream>>>(SLOTMAP, -1, NE * CAP);
  router_k<<<2048, 256, 0, stream>>>(x, wg, XB, TOPIDX, PROBS);
  hist_k<<<64, 256, 0, stream>>>(TOPIDX, BLKHIST);
  scan_k<<<1, 64, 0, stream>>>(BLKHIST, BLKOFF, TOTALS);
  rank_k<<<64, 256, 0, stream>>>(TOPIDX, BLKOFF, TOTALS, RANKS, SLOTMAP);

  unsigned short* CFCT   = (unsigned short*)(ws + oCFCT);
  unsigned short* CPROJT = (unsigned short*)(ws + oCPROJT);
  transpose_bf16_k<<<dim3(FCD / 64, CD / 64, NE), 256, 0, stream>>>(cfc, CFCT, CD, FCD);
  transpose_bf16_k<<<dim3(CD / 64, FCD / 64, NE), 256, 0, stream>>>(cproj, CPROJT, FCD, CD);

  size_t eoff = weights_end;
  auto ealloc = [&](size_t bytes) { size_t o = eoff; eoff = (eoff + bytes + 255) & ~(size_t)255; return o; };
  unsigned short* EO = (unsigned short*)(ws + ealloc(NE * EOSZ));
  unsigned short* H  = (unsigned short*)(ws + ealloc((size_t)EG * HSZ));

  for (int g = 0; g < NE / EG; ++g) {
    const int eb = g * EG;
    // G1: [cap x 1024] x [1024 x 4096] -> H (relu^2), gathered A. 256x256, 8 waves, 1280 blocks.
    gemm8_k<2, 4, 256, 256, CD, FCD, true, true>
        <<<EG * (CAP / 256) * (FCD / 256), 512, 0, stream>>>(
        XB, CFCT + (size_t)eb * FCD * CD, H, SLOTMAP, CNT, eb);
    // G2: [cap x 4096] x [4096 x 1024] -> EO. 128x128, 4 waves, 48KB LDS -> 3 blocks/CU, 1280 blocks.
    gemm8_k<2, 2, 128, 128, FCD, CD, false, false>
        <<<EG * (CAP / 128) * (CD / 128), 256, 0, stream>>>(
        H, CPROJT + (size_t)eb * CD * FCD, EO + (size_t)eb * CAP * CD, SLOTMAP, CNT, eb);
  }
  combine_k<<<NT, 256, 0, stream>>>(EO, TOPIDX, PROBS, RANKS, out);
}